// Round 3
// baseline (2213.748 us; speedup 1.0000x reference)
//
#include <hip/hip_runtime.h>
#include <math.h>

#define N_TOK 8192
#define DIM 1024
#define FF 4096
#define NE 8
#define SLOT_CAP (N_TOK*2 + NE*256)   // 18432
#define MAXT256 72
#define MAXT128 136

typedef float f32x4 __attribute__((ext_vector_type(4)));
typedef _Float16 f16x8 __attribute__((ext_vector_type(8)));
typedef unsigned int u32x4 __attribute__((ext_vector_type(4)));

__device__ __forceinline__ unsigned short f2h(float f) {
    _Float16 h = (_Float16)f;
    return __builtin_bit_cast(unsigned short, h);
}

__device__ __forceinline__ void gl_lds16(const void* g, void* l) {
    __builtin_amdgcn_global_load_lds(
        (const __attribute__((address_space(1))) void*)g,
        (__attribute__((address_space(3))) void*)l, 16, 0, 0);
}

__device__ __forceinline__ void vw8()  { asm volatile("s_waitcnt vmcnt(8)"   ::: "memory"); __builtin_amdgcn_sched_barrier(0); }
__device__ __forceinline__ void vw6()  { asm volatile("s_waitcnt vmcnt(6)"   ::: "memory"); __builtin_amdgcn_sched_barrier(0); }
__device__ __forceinline__ void vw0()  { asm volatile("s_waitcnt vmcnt(0)"   ::: "memory"); __builtin_amdgcn_sched_barrier(0); }
__device__ __forceinline__ void lw12() { asm volatile("s_waitcnt lgkmcnt(12)"::: "memory"); __builtin_amdgcn_sched_barrier(0); }
__device__ __forceinline__ void lw10() { asm volatile("s_waitcnt lgkmcnt(10)"::: "memory"); __builtin_amdgcn_sched_barrier(0); }
__device__ __forceinline__ void lw0()  { asm volatile("s_waitcnt lgkmcnt(0)" ::: "memory"); __builtin_amdgcn_sched_barrier(0); }

// ---------------- Router ----------------
__global__ __launch_bounds__(256) void k_router(
    const float* __restrict__ x, const float* __restrict__ Wr,
    unsigned short* __restrict__ xh, int* __restrict__ ctl,
    int* __restrict__ tok2e, float* __restrict__ tok2w)
{
    __shared__ float wr[NE * DIM];
    const int t = threadIdx.x;
#pragma unroll
    for (int i = 0; i < (NE * DIM) / 256; ++i) wr[i * 256 + t] = Wr[i * 256 + t];
    __syncthreads();

    const int lane = t & 63;
    const int n = blockIdx.x * 4 + (t >> 6);
    const float* xr = x + (size_t)n * DIM;
    unsigned short* xhr = xh + (size_t)n * DIM;

    float acc[NE];
#pragma unroll
    for (int e = 0; e < NE; ++e) acc[e] = 0.f;
#pragma unroll
    for (int j = 0; j < DIM / 64; ++j) {
        int d = j * 64 + lane;
        float v = xr[d];
        xhr[d] = f2h(v);
#pragma unroll
        for (int e = 0; e < NE; ++e) acc[e] += v * wr[e * DIM + d];
    }
#pragma unroll
    for (int off = 32; off >= 1; off >>= 1) {
#pragma unroll
        for (int e = 0; e < NE; ++e) acc[e] += __shfl_xor(acc[e], off);
    }
    if (lane == 0) {
        int e0 = 0; float v0 = acc[0];
#pragma unroll
        for (int e = 1; e < NE; ++e) if (acc[e] > v0) { v0 = acc[e]; e0 = e; }
        int e1 = -1; float v1 = -1e30f;
#pragma unroll
        for (int e = 0; e < NE; ++e) if (e != e0 && acc[e] > v1) { v1 = acc[e]; e1 = e; }
        float tt = expf(v1 - v0);
        tok2e[2 * n] = e0; tok2e[2 * n + 1] = e1;
        tok2w[2 * n] = 1.f / (1.f + tt); tok2w[2 * n + 1] = tt / (1.f + tt);
        atomicAdd(&ctl[e0], 1);
        atomicAdd(&ctl[e1], 1);
    }
}

// ---------------- Setup: offsets (pad 256), both tile maps, parallel pad fill ----------------
__global__ __launch_bounds__(256) void k_setup(
    int* __restrict__ ctl, int* __restrict__ tos, float* __restrict__ gos)
{
    __shared__ int sh[NE * 2];
    const int t = threadIdx.x;
    if (t == 0) {
        int run = 0, T = 0, T128 = 0;
        for (int e = 0; e < NE; ++e) {
            ctl[16 + e] = run;
            int c = ctl[e];
            sh[e] = run; sh[NE + e] = c;
            int mt = (c + 255) >> 8;
            for (int j = 0; j < mt; ++j) { ctl[40 + T] = e; ctl[112 + T] = run + j * 256; ++T; }
            int mt128 = (c + 127) >> 7;
            for (int j = 0; j < mt128; ++j) { ctl[184 + T128] = e; ctl[320 + T128] = run + j * 128; ++T128; }
            run += mt * 256;
        }
        ctl[16 + NE] = run;
        ctl[32] = T; ctl[33] = T128;
    }
    __syncthreads();
    for (int e = 0; e < NE; ++e) {
        int off = sh[e], c = sh[NE + e];
        int pad = ((c + 255) >> 8) << 8;
        for (int s = c + t; s < pad; s += 256) { tos[off + s] = 0; gos[off + s] = 0.f; }
    }
}

// ---------------- Scatter ----------------
__global__ __launch_bounds__(256) void k_scatter(
    const int* __restrict__ tok2e, const float* __restrict__ tok2w,
    int* __restrict__ ctl, int* __restrict__ tos, float* __restrict__ gos)
{
    const int n = blockIdx.x * 256 + threadIdx.x;
#pragma unroll
    for (int k = 0; k < 2; ++k) {
        int e = tok2e[2 * n + k];
        int pos = atomicAdd(&ctl[8 + e], 1);
        int slot = ctl[16 + e] + pos;
        tos[slot] = n;
        gos[slot] = tok2w[2 * n + k];
    }
}

// ---------------- W convert: fp32 [E][KD][ND] -> fp16 tile-format ----------------
// element (k = kt*64 + c*8 + j, n) at Wt[((e*KT+kt)*ND + n)*64 + (c ^ (n&7))*8 + j]
__global__ __launch_bounds__(256) void k_wcvt(
    const float* __restrict__ W, unsigned short* __restrict__ Wt, int KD, int ND)
{
    __shared__ unsigned short Lt[64 * 64];
    const int t = threadIdx.x;
    const int e = blockIdx.z, kt = blockIdx.y, n0 = blockIdx.x * 64;
    const int KT = KD >> 6;
    const float* src = W + (size_t)e * KD * ND + (size_t)(kt * 64) * ND + n0;
#pragma unroll
    for (int i = 0; i < 4; ++i) {
        int kl = (t >> 4) + i * 16;
        f32x4 r = *reinterpret_cast<const f32x4*>(src + (size_t)kl * ND + (t & 15) * 4);
        int j = kl & 7, co = kl >> 3;
#pragma unroll
        for (int m = 0; m < 4; ++m) {
            int nl = (t & 15) * 4 + m;
            Lt[nl * 64 + ((co ^ (nl & 7)) << 3) + j] = f2h(r[m]);
        }
    }
    __syncthreads();
    unsigned short* dst = Wt + ((size_t)(e * KT + kt) * ND + n0) * 64 + t * 16;
    *reinterpret_cast<u32x4*>(dst)     = *reinterpret_cast<const u32x4*>(&Lt[t * 16]);
    *reinterpret_cast<u32x4*>(dst + 8) = *reinterpret_cast<const u32x4*>(&Lt[t * 16 + 8]);
}

// ---------------- 256-tile pipelined grouped GEMM (8 waves, counted vmcnt/lgkmcnt) ----------------
template <int PHASE>
__global__ __launch_bounds__(512, 2) void k_gemm256(
    const unsigned short* __restrict__ Asrc, const unsigned short* __restrict__ Bh,
    unsigned short* __restrict__ Hout, float* __restrict__ Out,
    const int* __restrict__ ctl, const int* __restrict__ tos,
    const float* __restrict__ gos)
{
    constexpr int KD  = (PHASE == 1) ? DIM : FF;
    constexpr int ND  = (PHASE == 1) ? FF : DIM;
    constexpr int KT  = KD / 64;
    constexpr int BNp = (PHASE == 1) ? 256 : 128;
    constexpr int NFR = (PHASE == 1) ? 4 : 2;          // B frags / wave
    constexpr int ABYT = 32768;
    constexpr int BBYT = (PHASE == 1) ? 32768 : 16384;
    constexpr int BUFB = ABYT + BBYT;
    constexpr size_t ASTR = (PHASE == 1) ? 128 : (size_t)SLOT_CAP * 128;
    constexpr size_t BSTR = (size_t)ND * 128;

    const int tidx = blockIdx.y;
    if (tidx >= ctl[32]) return;
    const int e  = ctl[40 + tidx];
    const int m0 = ctl[112 + tidx];
    const int n0 = blockIdx.x * BNp;

    __shared__ __align__(1024) char lds[2 * BUFB];

    const int t = threadIdx.x, l = t & 63, w = t >> 6;
    const int wm = w >> 2, wn = w & 3;
    const int lin = w * 1024 + l * 16;

    // staging sources
    const char* ap0; const char* ap1; const char* ap2; const char* ap3;
    const char* pa = nullptr; const char* pb;
    if constexpr (PHASE == 1) {
        const int lrow = l >> 3, lchk = l & 7;
        const int swzb = (lchk ^ lrow) << 4;
        const int rb = w * 8 + lrow;
        ap0 = (const char*)Asrc + (size_t)tos[m0 + rb]       * (KD * 2) + swzb;
        ap1 = (const char*)Asrc + (size_t)tos[m0 + 64 + rb]  * (KD * 2) + swzb;
        ap2 = (const char*)Asrc + (size_t)tos[m0 + 128 + rb] * (KD * 2) + swzb;
        ap3 = (const char*)Asrc + (size_t)tos[m0 + 192 + rb] * (KD * 2) + swzb;
    } else {
        pa = (const char*)Asrc + (size_t)m0 * 128 + lin;
    }
    pb = (const char*)Bh + ((size_t)e * KT * ND + n0) * 128 + lin;

    char* ldsb = lds;
    int stbuf = 0;
    auto STAGE = [&]() {
        char* da = ldsb + stbuf * BUFB + w * 1024;
        char* db = ldsb + stbuf * BUFB + ABYT + w * 1024;
        if constexpr (PHASE == 1) {
            gl_lds16(ap0, da);           gl_lds16(ap1, da + 8192);
            gl_lds16(ap2, da + 16384);   gl_lds16(ap3, da + 24576);
            ap0 += 128; ap1 += 128; ap2 += 128; ap3 += 128;
        } else {
#pragma unroll
            for (int i = 0; i < 4; ++i) gl_lds16(pa + i * 8192, da + i * 8192);
            pa += ASTR;
        }
#pragma unroll
        for (int i = 0; i < BBYT / 8192; ++i) gl_lds16(pb + i * 8192, db + i * 8192);
        pb += BSTR;
        stbuf ^= 1;
    };

    // ds_read fragment bases (chunk-XOR baked; k-step1 = base ^ 64)
    const int snib = ((l >> 4) ^ (l & 7)) << 4;
    const int A0 = wm * 16384 + (l & 15) * 128 + snib;
    const int B0 = ((PHASE == 1) ? wn * 8192 : wn * 4096) + (l & 15) * 128 + snib;

    f16x8 a0[8], b0[NFR], a1[8], b1[NFR];
    f32x4 acc[8][NFR];
#pragma unroll
    for (int mi = 0; mi < 8; ++mi)
#pragma unroll
        for (int ni = 0; ni < NFR; ++ni) acc[mi][ni] = f32x4{0.f, 0.f, 0.f, 0.f};

    auto LDF0 = [&](int buf) {
        const char* qa = ldsb + buf * BUFB + A0;
        const char* qb = ldsb + buf * BUFB + ABYT + B0;
#pragma unroll
        for (int mi = 0; mi < 8; ++mi) a0[mi] = *(const f16x8*)(qa + mi * 2048);
#pragma unroll
        for (int ni = 0; ni < NFR; ++ni) b0[ni] = *(const f16x8*)(qb + ni * 2048);
    };
    auto LDF1 = [&](int buf) {
        const char* qa = ldsb + buf * BUFB + (A0 ^ 64);
        const char* qb = ldsb + buf * BUFB + ABYT + (B0 ^ 64);
#pragma unroll
        for (int mi = 0; mi < 8; ++mi) a1[mi] = *(const f16x8*)(qa + mi * 2048);
#pragma unroll
        for (int ni = 0; ni < NFR; ++ni) b1[ni] = *(const f16x8*)(qb + ni * 2048);
    };
    auto MM0 = [&]() {
        __builtin_amdgcn_s_setprio(1);
#pragma unroll
        for (int mi = 0; mi < 8; ++mi)
#pragma unroll
            for (int ni = 0; ni < NFR; ++ni)
                acc[mi][ni] = __builtin_amdgcn_mfma_f32_16x16x32_f16(a0[mi], b0[ni], acc[mi][ni], 0, 0, 0);
        __builtin_amdgcn_s_setprio(0);
    };
    auto MM1 = [&]() {
        __builtin_amdgcn_s_setprio(1);
#pragma unroll
        for (int mi = 0; mi < 8; ++mi)
#pragma unroll
            for (int ni = 0; ni < NFR; ++ni)
                acc[mi][ni] = __builtin_amdgcn_mfma_f32_16x16x32_f16(a1[mi], b1[ni], acc[mi][ni], 0, 0, 0);
        __builtin_amdgcn_s_setprio(0);
    };
    auto LWS = [&]() { if constexpr (PHASE == 1) lw12(); else lw10(); };
    auto VWS = [&]() { if constexpr (PHASE == 1) vw8();  else vw6();  };

    // prologue: stage tiles 0,1
    STAGE(); STAGE();
    VWS();                                  // tile 0 complete (tile 1 in flight)
    __builtin_amdgcn_s_barrier();
    int cur = 0;
    LDF0(cur);

    for (int kt = 0; kt < KT - 2; ++kt) {
        LDF1(cur);
        LWS();                              // set0 ready (set1's reads still pending)
        MM0();
        lw0();                              // set1 ready
        MM1();
        __builtin_amdgcn_s_barrier();       // all waves done reading buf[cur]
        STAGE();                            // tile kt+2 -> buf[cur]
        VWS();                              // tile kt+1 complete (kt+2 in flight)
        __builtin_amdgcn_s_barrier();
        cur ^= 1;
        LDF0(cur);
    }
    // kt = KT-2: no new stage; drain last tile
    LDF1(cur); LWS(); MM0(); lw0(); MM1();
    __builtin_amdgcn_s_barrier();
    vw0();
    __builtin_amdgcn_s_barrier();
    cur ^= 1;
    LDF0(cur);
    // kt = KT-1
    LDF1(cur); LWS(); MM0(); lw0(); MM1();

    // epilogue
#pragma unroll
    for (int mi = 0; mi < 8; ++mi) {
#pragma unroll
        for (int rr = 0; rr < 4; ++rr) {
            const int srow = m0 + wm * 128 + mi * 16 + (l >> 4) * 4 + rr;
            if constexpr (PHASE == 1) {
#pragma unroll
                for (int ni = 0; ni < NFR; ++ni) {
                    int col = n0 + wn * 64 + ni * 16 + (l & 15);
                    float v = acc[mi][ni][rr];
                    float g = 0.5f * v * (1.f + erff(v * 0.70710678118654752f));
                    int kl = col & 63;
                    Hout[((size_t)(col >> 6) * SLOT_CAP + srow) * 64 +
                         (((kl >> 3) ^ (srow & 7)) << 3) + (kl & 7)] = f2h(g);
                }
            } else {
                int tok = tos[srow];
                float gate = gos[srow];
                float* orow = Out + (size_t)tok * DIM + n0 + wn * 32 + (l & 15);
#pragma unroll
                for (int ni = 0; ni < NFR; ++ni)
                    atomicAdd(&orow[ni * 16], gate * acc[mi][ni][rr]);
            }
        }
    }
}

// ---------------- Fallback 128-tile GEMM (reg-staged fp32 B) ----------------
template <int PHASE>
__global__ __launch_bounds__(256) void k_gemm_fb(
    const unsigned short* __restrict__ Asrc, const float* __restrict__ Bf,
    unsigned short* __restrict__ Hout, float* __restrict__ Out,
    const int* __restrict__ ctl, const int* __restrict__ tos,
    const float* __restrict__ gos)
{
    constexpr int KD = (PHASE == 1) ? DIM : FF;
    constexpr int ND = (PHASE == 1) ? FF : DIM;
    constexpr int KT = KD / 64;

    const int tidx = blockIdx.y;
    if (tidx >= ctl[33]) return;
    const int e  = ctl[184 + tidx];
    const int m0 = ctl[320 + tidx];
    const int n0 = blockIdx.x * 128;

    __shared__ __align__(16) unsigned short Al[128 * 64];
    __shared__ __align__(16) unsigned short Bl[128 * 64];
    char* Alc = (char*)Al;
    char* Blc = (char*)Bl;

    const int t = threadIdx.x, lane = t & 63, wv = t >> 6;
    const int wm = wv >> 1, wn = wv & 1;

    const unsigned short* asrc[4];
    if (PHASE == 1) {
        const int swz = ((lane & 7) ^ (lane >> 3)) * 8;
#pragma unroll
        for (int i = 0; i < 4; ++i) {
            int row = i * 32 + wv * 8 + (lane >> 3);
            asrc[i] = Asrc + (size_t)tos[m0 + row] * KD + swz;
        }
    }
    const int lin = wv * 512 + lane * 8;

    f32x4 acc[4][4];
#pragma unroll
    for (int a = 0; a < 4; ++a)
#pragma unroll
        for (int b = 0; b < 4; ++b) acc[a][b] = f32x4{0.f, 0.f, 0.f, 0.f};

    for (int kt = 0; kt < KT; ++kt) {
        if (PHASE == 1) {
#pragma unroll
            for (int i = 0; i < 4; ++i)
                gl_lds16(asrc[i] + kt * 64, Al + i * 2048 + wv * 512);
        } else {
            const unsigned short* ab = Asrc + ((size_t)kt * SLOT_CAP + m0) * 64;
#pragma unroll
            for (int i = 0; i < 4; ++i)
                gl_lds16(ab + i * 2048 + lin, Al + i * 2048 + wv * 512);
        }
        {
            const float* Wf = Bf + (size_t)e * KD * ND;
            const int kb = (wv >> 1) * 32 + (lane >> 4) * 8;
            const int n4 = (wv & 1) * 64 + (lane & 15) * 4;
            f32x4 r[8];
#pragma unroll
            for (int rr = 0; rr < 8; ++rr)
                r[rr] = *reinterpret_cast<const f32x4*>(
                    Wf + (size_t)(kt * 64 + kb + rr) * ND + n0 + n4);
#pragma unroll
            for (int m = 0; m < 4; ++m) {
                f16x8 v;
#pragma unroll
                for (int rr = 0; rr < 8; ++rr) v[rr] = (_Float16)r[rr][m];
                int nn = n4 + m;
                *reinterpret_cast<f16x8*>(Blc + nn * 128 + (((kb >> 3) ^ (nn & 7)) << 4)) = v;
            }
        }
        __syncthreads();
#pragma unroll
        for (int kc = 0; kc < 2; ++kc) {
            const int cb = kc * 4 + (lane >> 4);
            f16x8 af[4], bf[4];
#pragma unroll
            for (int mi = 0; mi < 4; ++mi) {
                int row = wm * 64 + mi * 16 + (lane & 15);
                af[mi] = *reinterpret_cast<const f16x8*>(Alc + row * 128 + ((cb ^ (row & 7)) << 4));
            }
#pragma unroll
            for (int ni = 0; ni < 4; ++ni) {
                int col = wn * 64 + ni * 16 + (lane & 15);
                bf[ni] = *reinterpret_cast<const f16x8*>(Blc + col * 128 + ((cb ^ (col & 7)) << 4));
            }
#pragma unroll
            for (int mi = 0; mi < 4; ++mi)
#pragma unroll
                for (int ni = 0; ni < 4; ++ni)
                    acc[mi][ni] = __builtin_amdgcn_mfma_f32_16x16x32_f16(
                        af[mi], bf[ni], acc[mi][ni], 0, 0, 0);
        }
        __syncthreads();
    }

#pragma unroll
    for (int mi = 0; mi < 4; ++mi) {
#pragma unroll
        for (int rr = 0; rr < 4; ++rr) {
            const int srow = m0 + wm * 64 + mi * 16 + (lane >> 4) * 4 + rr;
            if (PHASE == 1) {
#pragma unroll
                for (int ni = 0; ni < 4; ++ni) {
                    int col = n0 + wn * 64 + ni * 16 + (lane & 15);
                    float v = acc[mi][ni][rr];
                    float g = 0.5f * v * (1.f + erff(v * 0.70710678118654752f));
                    int kl = col & 63;
                    Hout[((size_t)(col >> 6) * SLOT_CAP + srow) * 64 +
                         (((kl >> 3) ^ (srow & 7)) << 3) + (kl & 7)] = f2h(g);
                }
            } else {
                int tok = tos[srow];
                float gate = gos[srow];
                float* orow = Out + (size_t)tok * DIM + n0 + wn * 64 + (lane & 15);
#pragma unroll
                for (int ni = 0; ni < 4; ++ni)
                    atomicAdd(&orow[ni * 16], gate * acc[mi][ni][rr]);
            }
        }
    }
}

// ---------------- launch ----------------
extern "C" void kernel_launch(void* const* d_in, const int* in_sizes, int n_in,
                              void* d_out, int out_size, void* d_ws, size_t ws_size,
                              hipStream_t stream) {
    (void)in_sizes; (void)n_in;
    const float* x  = (const float*)d_in[0];
    const float* Wr = (const float*)d_in[1];
    const float* W1 = (const float*)d_in[2];
    const float* W2 = (const float*)d_in[3];
    float* out = (float*)d_out;
    char* ws = (char*)d_ws;

    // ws layout (bytes):
    //   0          ctl (4 KB)
    //   4096       tok2e (64 KB)
    //   69632      tok2w (64 KB)
    //   135168     tos (18432*4)
    //   208896     gos (18432*4)
    //   282624     xh fp16 (16 MB)            -> 17,059,840
    //   17059840   H2 fp16 tile-fmt (151 MB)  -> 168,054,784
    //   168054784  Wt fp16 (64 MB, reused)    -> 235,163,648
    const size_t NEED_FB   = 168054784ULL;
    const size_t NEED_FULL = 235163648ULL;
    if (ws_size < NEED_FB) return;
    const bool big = ws_size >= NEED_FULL;

    int*            ctl = (int*)(ws + 0);
    int*            t2e = (int*)(ws + 4096);
    float*          t2w = (float*)(ws + 69632);
    int*            tos = (int*)(ws + 135168);
    float*          gos = (float*)(ws + 208896);
    unsigned short* xh  = (unsigned short*)(ws + 282624);
    unsigned short* H2  = (unsigned short*)(ws + 17059840);
    unsigned short* Wt  = (unsigned short*)(ws + 168054784);

    hipMemsetAsync(ctl, 0, 64, stream);
    hipMemsetAsync(d_out, 0, (size_t)out_size * 4, stream);

    k_router <<<dim3(N_TOK / 4), dim3(256), 0, stream>>>(x, Wr, xh, ctl, t2e, t2w);
    k_setup  <<<dim3(1), dim3(256), 0, stream>>>(ctl, tos, gos);
    k_scatter<<<dim3(N_TOK / 256), dim3(256), 0, stream>>>(t2e, t2w, ctl, tos, gos);

    if (big) {
        k_wcvt<<<dim3(64, 16, 8), dim3(256), 0, stream>>>(W1, Wt, DIM, FF);
        k_gemm256<1><<<dim3(FF / 256, MAXT256), dim3(512), 0, stream>>>(
            xh, Wt, H2, nullptr, ctl, tos, gos);
        k_wcvt<<<dim3(16, 64, 8), dim3(256), 0, stream>>>(W2, Wt, FF, DIM);
        k_gemm256<2><<<dim3(DIM / 128, MAXT256), dim3(512), 0, stream>>>(
            H2, Wt, nullptr, out, ctl, tos, gos);
    } else {
        k_gemm_fb<1><<<dim3(FF / 128, MAXT128), dim3(256), 0, stream>>>(
            xh, W1, H2, nullptr, ctl, tos, gos);
        k_gemm_fb<2><<<dim3(DIM / 128, MAXT128), dim3(256), 0, stream>>>(
            H2, W2, nullptr, out, ctl, tos, gos);
    }
}

// Round 4
// 928.713 us; speedup vs baseline: 2.3837x; 2.3837x over previous
//
#include <hip/hip_runtime.h>
#include <math.h>

#define N_TOK 8192
#define DIM 1024
#define FF 4096
#define NE 8
#define SLOT_CAP (N_TOK*2 + NE*256)   // 18432
#define MAXT256 72
#define MAXT128 136

typedef float f32x4 __attribute__((ext_vector_type(4)));
typedef _Float16 f16x8 __attribute__((ext_vector_type(8)));
typedef unsigned int u32x4 __attribute__((ext_vector_type(4)));

__device__ __forceinline__ unsigned short f2h(float f) {
    _Float16 h = (_Float16)f;
    return __builtin_bit_cast(unsigned short, h);
}

__device__ __forceinline__ void gl_lds16(const void* g, void* l) {
    __builtin_amdgcn_global_load_lds(
        (const __attribute__((address_space(1))) void*)g,
        (__attribute__((address_space(3))) void*)l, 16, 0, 0);
}

__device__ __forceinline__ void vw0() { asm volatile("s_waitcnt vmcnt(0)"  ::: "memory"); __builtin_amdgcn_sched_barrier(0); }
__device__ __forceinline__ void lw0() { asm volatile("s_waitcnt lgkmcnt(0)"::: "memory"); __builtin_amdgcn_sched_barrier(0); }

// counted waits, parameterized on PHASE at compile time
#define VWN() do { if constexpr (PHASE == 1) asm volatile("s_waitcnt vmcnt(8)" ::: "memory"); \
                   else                      asm volatile("s_waitcnt vmcnt(6)" ::: "memory"); \
                   __builtin_amdgcn_sched_barrier(0); } while (0)
#define LWN() do { if constexpr (PHASE == 1) asm volatile("s_waitcnt lgkmcnt(8)" ::: "memory"); \
                   else                      asm volatile("s_waitcnt lgkmcnt(6)" ::: "memory"); \
                   __builtin_amdgcn_sched_barrier(0); } while (0)

// ---------------- Router ----------------
__global__ __launch_bounds__(256) void k_router(
    const float* __restrict__ x, const float* __restrict__ Wr,
    unsigned short* __restrict__ xh, int* __restrict__ ctl,
    int* __restrict__ tok2e, float* __restrict__ tok2w)
{
    __shared__ float wr[NE * DIM];
    const int t = threadIdx.x;
#pragma unroll
    for (int i = 0; i < (NE * DIM) / 256; ++i) wr[i * 256 + t] = Wr[i * 256 + t];
    __syncthreads();

    const int lane = t & 63;
    const int n = blockIdx.x * 4 + (t >> 6);
    const float* xr = x + (size_t)n * DIM;
    unsigned short* xhr = xh + (size_t)n * DIM;

    float acc[NE];
#pragma unroll
    for (int e = 0; e < NE; ++e) acc[e] = 0.f;
#pragma unroll
    for (int j = 0; j < DIM / 64; ++j) {
        int d = j * 64 + lane;
        float v = xr[d];
        xhr[d] = f2h(v);
#pragma unroll
        for (int e = 0; e < NE; ++e) acc[e] += v * wr[e * DIM + d];
    }
#pragma unroll
    for (int off = 32; off >= 1; off >>= 1) {
#pragma unroll
        for (int e = 0; e < NE; ++e) acc[e] += __shfl_xor(acc[e], off);
    }
    if (lane == 0) {
        int e0 = 0; float v0 = acc[0];
#pragma unroll
        for (int e = 1; e < NE; ++e) if (acc[e] > v0) { v0 = acc[e]; e0 = e; }
        int e1 = -1; float v1 = -1e30f;
#pragma unroll
        for (int e = 0; e < NE; ++e) if (e != e0 && acc[e] > v1) { v1 = acc[e]; e1 = e; }
        float tt = expf(v1 - v0);
        tok2e[2 * n] = e0; tok2e[2 * n + 1] = e1;
        tok2w[2 * n] = 1.f / (1.f + tt); tok2w[2 * n + 1] = tt / (1.f + tt);
        atomicAdd(&ctl[e0], 1);
        atomicAdd(&ctl[e1], 1);
    }
}

// ---------------- Setup: offsets (pad 256), both tile maps, parallel pad fill ----------------
__global__ __launch_bounds__(256) void k_setup(
    int* __restrict__ ctl, int* __restrict__ tos, float* __restrict__ gos)
{
    __shared__ int sh[NE * 2];
    const int t = threadIdx.x;
    if (t == 0) {
        int run = 0, T = 0, T128 = 0;
        for (int e = 0; e < NE; ++e) {
            ctl[16 + e] = run;
            int c = ctl[e];
            sh[e] = run; sh[NE + e] = c;
            int mt = (c + 255) >> 8;
            for (int j = 0; j < mt; ++j) { ctl[40 + T] = e; ctl[112 + T] = run + j * 256; ++T; }
            int mt128 = (c + 127) >> 7;
            for (int j = 0; j < mt128; ++j) { ctl[184 + T128] = e; ctl[320 + T128] = run + j * 128; ++T128; }
            run += mt * 256;
        }
        ctl[16 + NE] = run;
        ctl[32] = T; ctl[33] = T128;
    }
    __syncthreads();
    for (int e = 0; e < NE; ++e) {
        int off = sh[e], c = sh[NE + e];
        int pad = ((c + 255) >> 8) << 8;
        for (int s = c + t; s < pad; s += 256) { tos[off + s] = 0; gos[off + s] = 0.f; }
    }
}

// ---------------- Scatter ----------------
__global__ __launch_bounds__(256) void k_scatter(
    const int* __restrict__ tok2e, const float* __restrict__ tok2w,
    int* __restrict__ ctl, int* __restrict__ tos, float* __restrict__ gos)
{
    const int n = blockIdx.x * 256 + threadIdx.x;
#pragma unroll
    for (int k = 0; k < 2; ++k) {
        int e = tok2e[2 * n + k];
        int pos = atomicAdd(&ctl[8 + e], 1);
        int slot = ctl[16 + e] + pos;
        tos[slot] = n;
        gos[slot] = tok2w[2 * n + k];
    }
}

// ---------------- W convert: fp32 [E][KD][ND] -> fp16 tile-format ----------------
// element (k = kt*64 + c*8 + j, n) at Wt[((e*KT+kt)*ND + n)*64 + (c ^ (n&7))*8 + j]
__global__ __launch_bounds__(256) void k_wcvt(
    const float* __restrict__ W, unsigned short* __restrict__ Wt, int KD, int ND)
{
    __shared__ unsigned short Lt[64 * 64];
    const int t = threadIdx.x;
    const int e = blockIdx.z, kt = blockIdx.y, n0 = blockIdx.x * 64;
    const int KT = KD >> 6;
    const float* src = W + (size_t)e * KD * ND + (size_t)(kt * 64) * ND + n0;
#pragma unroll
    for (int i = 0; i < 4; ++i) {
        int kl = (t >> 4) + i * 16;
        f32x4 r = *reinterpret_cast<const f32x4*>(src + (size_t)kl * ND + (t & 15) * 4);
        int j = kl & 7, co = kl >> 3;
#pragma unroll
        for (int m = 0; m < 4; ++m) {
            int nl = (t & 15) * 4 + m;
            Lt[nl * 64 + ((co ^ (nl & 7)) << 3) + j] = f2h(r[m]);
        }
    }
    __syncthreads();
    unsigned short* dst = Wt + ((size_t)(e * KT + kt) * ND + n0) * 64 + t * 16;
    *reinterpret_cast<u32x4*>(dst)     = *reinterpret_cast<const u32x4*>(&Lt[t * 16]);
    *reinterpret_cast<u32x4*>(dst + 8) = *reinterpret_cast<const u32x4*>(&Lt[t * 16 + 8]);
}

// ---- phase fragment load / mfma macros (compile-time indices only) ----
#define LDP(SET, PH, BASE) do {                                              \
    const char* qa_ = (BASE) + (A0 ^ (((PH) >> 1) * 64)) + (((PH) & 1) * 8192); \
    af##SET[0] = *(const f16x8*)(qa_);                                      \
    af##SET[1] = *(const f16x8*)(qa_ + 2048);                                \
    af##SET[2] = *(const f16x8*)(qa_ + 4096);                                \
    af##SET[3] = *(const f16x8*)(qa_ + 6144);                                \
    const char* qb_ = (BASE) + ABYT + (B0 ^ (((PH) >> 1) * 64));             \
    _Pragma("unroll")                                                        \
    for (int ni_ = 0; ni_ < NFR; ++ni_)                                      \
        bf##SET[ni_] = *(const f16x8*)(qb_ + ni_ * 2048);                    \
} while (0)

#define MMP(SET, PH) do {                                                    \
    __builtin_amdgcn_s_setprio(1);                                           \
    _Pragma("unroll")                                                        \
    for (int j_ = 0; j_ < 4; ++j_)                                           \
        _Pragma("unroll")                                                    \
        for (int ni_ = 0; ni_ < NFR; ++ni_)                                  \
            acc[((PH) & 1) * 4 + j_][ni_] = __builtin_amdgcn_mfma_f32_16x16x32_f16( \
                af##SET[j_], bf##SET[ni_], acc[((PH) & 1) * 4 + j_][ni_], 0, 0, 0); \
    __builtin_amdgcn_s_setprio(0);                                           \
} while (0)

// ---------------- 256-tile pipelined grouped GEMM (8 waves, 4-phase K-tile) ----------------
template <int PHASE>
__global__ __launch_bounds__(512, 1) void k_gemm256(
    const unsigned short* __restrict__ Asrc, const unsigned short* __restrict__ Bh,
    unsigned short* __restrict__ Hout, float* __restrict__ Out,
    const int* __restrict__ ctl, const int* __restrict__ tos,
    const float* __restrict__ gos)
{
    constexpr int KD  = (PHASE == 1) ? DIM : FF;
    constexpr int ND  = (PHASE == 1) ? FF : DIM;
    constexpr int KT  = KD / 64;
    constexpr int BNp = (PHASE == 1) ? 256 : 128;
    constexpr int NFR = (PHASE == 1) ? 4 : 2;          // B frags / wave
    constexpr int ABYT = 32768;
    constexpr int BBYT = BNp * 128;                    // 32768 / 16384
    constexpr int BUFB = ABYT + BBYT;
    constexpr size_t ASTR = (PHASE == 1) ? 128 : (size_t)SLOT_CAP * 128;
    constexpr size_t BSTR = (size_t)ND * 128;

    const int tidx = blockIdx.y;
    if (tidx >= ctl[32]) return;
    const int e  = ctl[40 + tidx];
    const int m0 = ctl[112 + tidx];
    const int n0 = blockIdx.x * BNp;

    __shared__ __align__(1024) char lds[2 * BUFB];

    const int t = threadIdx.x, l = t & 63, w = t >> 6;
    const int wm = w >> 2, wn = w & 3;
    const int lin = w * 1024 + l * 16;

    // staging sources
    const char* ap0; const char* ap1; const char* ap2; const char* ap3;
    const char* pa = nullptr; const char* pb;
    if constexpr (PHASE == 1) {
        const int lrow = l >> 3, lchk = l & 7;
        const int swzb = (lchk ^ lrow) << 4;
        const int rb = w * 8 + lrow;
        ap0 = (const char*)Asrc + (size_t)tos[m0 + rb]       * (KD * 2) + swzb;
        ap1 = (const char*)Asrc + (size_t)tos[m0 + 64 + rb]  * (KD * 2) + swzb;
        ap2 = (const char*)Asrc + (size_t)tos[m0 + 128 + rb] * (KD * 2) + swzb;
        ap3 = (const char*)Asrc + (size_t)tos[m0 + 192 + rb] * (KD * 2) + swzb;
    } else {
        pa = (const char*)Asrc + (size_t)m0 * 128 + lin;
    }
    pb = (const char*)Bh + ((size_t)e * KT * ND + n0) * 128 + lin;

    int stbuf = 0;
    auto STAGE = [&]() {
        char* da = lds + stbuf * BUFB + w * 1024;
        char* db = lds + stbuf * BUFB + ABYT + w * 1024;
        if constexpr (PHASE == 1) {
            gl_lds16(ap0, da);           gl_lds16(ap1, da + 8192);
            gl_lds16(ap2, da + 16384);   gl_lds16(ap3, da + 24576);
            ap0 += 128; ap1 += 128; ap2 += 128; ap3 += 128;
        } else {
#pragma unroll
            for (int i = 0; i < 4; ++i) gl_lds16(pa + i * 8192, da + i * 8192);
            pa += ASTR;
        }
#pragma unroll
        for (int i = 0; i < BBYT / 8192; ++i) gl_lds16(pb + i * 8192, db + i * 8192);
        pb += BSTR;
        stbuf ^= 1;
    };

    // ds_read fragment bases (chunk-XOR baked; k-half 1 = base ^ 64)
    const int snib = ((l >> 4) ^ (l & 7)) << 4;
    const int A0 = wm * 16384 + (l & 15) * 128 + snib;
    const int B0 = ((PHASE == 1) ? wn * 8192 : wn * 4096) + (l & 15) * 128 + snib;

    f16x8 afA[4], bfA[NFR], afB[4], bfB[NFR];
    f32x4 acc[8][NFR];
#pragma unroll
    for (int mi = 0; mi < 8; ++mi)
#pragma unroll
        for (int ni = 0; ni < NFR; ++ni) acc[mi][ni] = f32x4{0.f, 0.f, 0.f, 0.f};

    // prologue: stage tiles 0,1
    int cur = 0;
    STAGE(); STAGE();
    VWN();                                  // tile 0 landed (tile 1 in flight)
    __builtin_amdgcn_s_barrier();
    LDP(A, 0, lds + cur);

    for (int kt = 0; kt < KT - 2; ++kt) {
        const char* cb = lds + cur;
        LDP(B, 1, cb); LWN(); MMP(A, 0);
        LDP(A, 2, cb); LWN(); MMP(B, 1);
        LDP(B, 3, cb); LWN(); MMP(A, 2);
        lw0();                              // all own reads from buf cur done
        __builtin_amdgcn_s_barrier();       // everyone done reading buf cur
        STAGE();                            // tile kt+2 -> buf cur
        MMP(B, 3);
        VWN();                              // tile kt+1 landed (kt+2 in flight)
        __builtin_amdgcn_s_barrier();
        cur ^= BUFB;
        LDP(A, 0, lds + cur);
    }
    // tile KT-2 (no further staging)
    {
        const char* cb = lds + cur;
        LDP(B, 1, cb); LWN(); MMP(A, 0);
        LDP(A, 2, cb); LWN(); MMP(B, 1);
        LDP(B, 3, cb); LWN(); MMP(A, 2);
        lw0(); MMP(B, 3);
        vw0();                              // tile KT-1 fully landed
        __builtin_amdgcn_s_barrier();
        cur ^= BUFB;
        LDP(A, 0, lds + cur);
    }
    // tile KT-1
    {
        const char* cb = lds + cur;
        LDP(B, 1, cb); LWN(); MMP(A, 0);
        LDP(A, 2, cb); LWN(); MMP(B, 1);
        LDP(B, 3, cb); LWN(); MMP(A, 2);
        lw0(); MMP(B, 3);
    }

    // epilogue
#pragma unroll
    for (int mi = 0; mi < 8; ++mi) {
#pragma unroll
        for (int rr = 0; rr < 4; ++rr) {
            const int srow = m0 + wm * 128 + mi * 16 + (l >> 4) * 4 + rr;
            if constexpr (PHASE == 1) {
#pragma unroll
                for (int ni = 0; ni < NFR; ++ni) {
                    int col = n0 + wn * 64 + ni * 16 + (l & 15);
                    float v = acc[mi][ni][rr];
                    float g = 0.5f * v * (1.f + erff(v * 0.70710678118654752f));
                    int kl = col & 63;
                    Hout[((size_t)(col >> 6) * SLOT_CAP + srow) * 64 +
                         (((kl >> 3) ^ (srow & 7)) << 3) + (kl & 7)] = f2h(g);
                }
            } else {
                int tok = tos[srow];
                float gate = gos[srow];
                float* orow = Out + (size_t)tok * DIM + n0 + wn * 32 + (l & 15);
#pragma unroll
                for (int ni = 0; ni < NFR; ++ni)
                    atomicAdd(&orow[ni * 16], gate * acc[mi][ni][rr]);
            }
        }
    }
}

// ---------------- Fallback 128-tile GEMM (reg-staged fp32 B) ----------------
template <int PHASE>
__global__ __launch_bounds__(256) void k_gemm_fb(
    const unsigned short* __restrict__ Asrc, const float* __restrict__ Bf,
    unsigned short* __restrict__ Hout, float* __restrict__ Out,
    const int* __restrict__ ctl, const int* __restrict__ tos,
    const float* __restrict__ gos)
{
    constexpr int KD = (PHASE == 1) ? DIM : FF;
    constexpr int ND = (PHASE == 1) ? FF : DIM;
    constexpr int KT = KD / 64;

    const int tidx = blockIdx.y;
    if (tidx >= ctl[33]) return;
    const int e  = ctl[184 + tidx];
    const int m0 = ctl[320 + tidx];
    const int n0 = blockIdx.x * 128;

    __shared__ __align__(16) unsigned short Al[128 * 64];
    __shared__ __align__(16) unsigned short Bl[128 * 64];
    char* Alc = (char*)Al;
    char* Blc = (char*)Bl;

    const int t = threadIdx.x, lane = t & 63, wv = t >> 6;
    const int wm = wv >> 1, wn = wv & 1;

    const unsigned short* asrc[4];
    if (PHASE == 1) {
        const int swz = ((lane & 7) ^ (lane >> 3)) * 8;
#pragma unroll
        for (int i = 0; i < 4; ++i) {
            int row = i * 32 + wv * 8 + (lane >> 3);
            asrc[i] = Asrc + (size_t)tos[m0 + row] * KD + swz;
        }
    }
    const int lin = wv * 512 + lane * 8;

    f32x4 acc[4][4];
#pragma unroll
    for (int a = 0; a < 4; ++a)
#pragma unroll
        for (int b = 0; b < 4; ++b) acc[a][b] = f32x4{0.f, 0.f, 0.f, 0.f};

    for (int kt = 0; kt < KT; ++kt) {
        if (PHASE == 1) {
#pragma unroll
            for (int i = 0; i < 4; ++i)
                gl_lds16(asrc[i] + kt * 64, Al + i * 2048 + wv * 512);
        } else {
            const unsigned short* ab = Asrc + ((size_t)kt * SLOT_CAP + m0) * 64;
#pragma unroll
            for (int i = 0; i < 4; ++i)
                gl_lds16(ab + i * 2048 + lin, Al + i * 2048 + wv * 512);
        }
        {
            const float* Wf = Bf + (size_t)e * KD * ND;
            const int kb = (wv >> 1) * 32 + (lane >> 4) * 8;
            const int n4 = (wv & 1) * 64 + (lane & 15) * 4;
            f32x4 r[8];
#pragma unroll
            for (int rr = 0; rr < 8; ++rr)
                r[rr] = *reinterpret_cast<const f32x4*>(
                    Wf + (size_t)(kt * 64 + kb + rr) * ND + n0 + n4);
#pragma unroll
            for (int m = 0; m < 4; ++m) {
                f16x8 v;
#pragma unroll
                for (int rr = 0; rr < 8; ++rr) v[rr] = (_Float16)r[rr][m];
                int nn = n4 + m;
                *reinterpret_cast<f16x8*>(Blc + nn * 128 + (((kb >> 3) ^ (nn & 7)) << 4)) = v;
            }
        }
        __syncthreads();
#pragma unroll
        for (int kc = 0; kc < 2; ++kc) {
            const int cb = kc * 4 + (lane >> 4);
            f16x8 af[4], bf[4];
#pragma unroll
            for (int mi = 0; mi < 4; ++mi) {
                int row = wm * 64 + mi * 16 + (lane & 15);
                af[mi] = *reinterpret_cast<const f16x8*>(Alc + row * 128 + ((cb ^ (row & 7)) << 4));
            }
#pragma unroll
            for (int ni = 0; ni < 4; ++ni) {
                int col = wn * 64 + ni * 16 + (lane & 15);
                bf[ni] = *reinterpret_cast<const f16x8*>(Blc + col * 128 + ((cb ^ (col & 7)) << 4));
            }
#pragma unroll
            for (int mi = 0; mi < 4; ++mi)
#pragma unroll
                for (int ni = 0; ni < 4; ++ni)
                    acc[mi][ni] = __builtin_amdgcn_mfma_f32_16x16x32_f16(
                        af[mi], bf[ni], acc[mi][ni], 0, 0, 0);
        }
        __syncthreads();
    }

#pragma unroll
    for (int mi = 0; mi < 4; ++mi) {
#pragma unroll
        for (int rr = 0; rr < 4; ++rr) {
            const int srow = m0 + wm * 64 + mi * 16 + (lane >> 4) * 4 + rr;
            if (PHASE == 1) {
#pragma unroll
                for (int ni = 0; ni < 4; ++ni) {
                    int col = n0 + wn * 64 + ni * 16 + (lane & 15);
                    float v = acc[mi][ni][rr];
                    float g = 0.5f * v * (1.f + erff(v * 0.70710678118654752f));
                    int kl = col & 63;
                    Hout[((size_t)(col >> 6) * SLOT_CAP + srow) * 64 +
                         (((kl >> 3) ^ (srow & 7)) << 3) + (kl & 7)] = f2h(g);
                }
            } else {
                int tok = tos[srow];
                float gate = gos[srow];
                float* orow = Out + (size_t)tok * DIM + n0 + wn * 64 + (lane & 15);
#pragma unroll
                for (int ni = 0; ni < 4; ++ni)
                    atomicAdd(&orow[ni * 16], gate * acc[mi][ni][rr]);
            }
        }
    }
}

// ---------------- launch ----------------
extern "C" void kernel_launch(void* const* d_in, const int* in_sizes, int n_in,
                              void* d_out, int out_size, void* d_ws, size_t ws_size,
                              hipStream_t stream) {
    (void)in_sizes; (void)n_in;
    const float* x  = (const float*)d_in[0];
    const float* Wr = (const float*)d_in[1];
    const float* W1 = (const float*)d_in[2];
    const float* W2 = (const float*)d_in[3];
    float* out = (float*)d_out;
    char* ws = (char*)d_ws;

    // ws layout (bytes):
    //   0          ctl (4 KB)
    //   4096       tok2e (64 KB)
    //   69632      tok2w (64 KB)
    //   135168     tos (18432*4)
    //   208896     gos (18432*4)
    //   282624     xh fp16 (16 MB)            -> 17,059,840
    //   17059840   H2 fp16 tile-fmt (151 MB)  -> 168,054,784
    //   168054784  Wt fp16 (64 MB, reused)    -> 235,163,648
    const size_t NEED_FB   = 168054784ULL;
    const size_t NEED_FULL = 235163648ULL;
    if (ws_size < NEED_FB) return;
    const bool big = ws_size >= NEED_FULL;

    int*            ctl = (int*)(ws + 0);
    int*            t2e = (int*)(ws + 4096);
    float*          t2w = (float*)(ws + 69632);
    int*            tos = (int*)(ws + 135168);
    float*          gos = (float*)(ws + 208896);
    unsigned short* xh  = (unsigned short*)(ws + 282624);
    unsigned short* H2  = (unsigned short*)(ws + 17059840);
    unsigned short* Wt  = (unsigned short*)(ws + 168054784);

    hipMemsetAsync(ctl, 0, 64, stream);
    hipMemsetAsync(d_out, 0, (size_t)out_size * 4, stream);

    k_router <<<dim3(N_TOK / 4), dim3(256), 0, stream>>>(x, Wr, xh, ctl, t2e, t2w);
    k_setup  <<<dim3(1), dim3(256), 0, stream>>>(ctl, tos, gos);
    k_scatter<<<dim3(N_TOK / 256), dim3(256), 0, stream>>>(t2e, t2w, ctl, tos, gos);

    if (big) {
        k_wcvt<<<dim3(64, 16, 8), dim3(256), 0, stream>>>(W1, Wt, DIM, FF);
        k_gemm256<1><<<dim3(FF / 256, MAXT256), dim3(512), 0, stream>>>(
            xh, Wt, H2, nullptr, ctl, tos, gos);
        k_wcvt<<<dim3(16, 64, 8), dim3(256), 0, stream>>>(W2, Wt, FF, DIM);
        k_gemm256<2><<<dim3(DIM / 128, MAXT256), dim3(512), 0, stream>>>(
            H2, Wt, nullptr, out, ctl, tos, gos);
    } else {
        k_gemm_fb<1><<<dim3(FF / 128, MAXT128), dim3(256), 0, stream>>>(
            xh, W1, H2, nullptr, ctl, tos, gos);
        k_gemm_fb<2><<<dim3(DIM / 128, MAXT128), dim3(256), 0, stream>>>(
            H2, W2, nullptr, out, ctl, tos, gos);
    }
}

// Round 5
// 816.983 us; speedup vs baseline: 2.7097x; 1.1368x over previous
//
#include <hip/hip_runtime.h>
#include <math.h>

#define N_TOK 8192
#define DIM 1024
#define FF 4096
#define NE 8
#define SLOT_CAP (N_TOK*2 + NE*128)   // 17408
#define MAXT 136

typedef float f32x4 __attribute__((ext_vector_type(4)));
typedef _Float16 f16x8 __attribute__((ext_vector_type(8)));
typedef unsigned int u32x4 __attribute__((ext_vector_type(4)));

__device__ __forceinline__ unsigned short f2h(float f) {
    _Float16 h = (_Float16)f;
    return __builtin_bit_cast(unsigned short, h);
}

__device__ __forceinline__ void gl_lds16(const void* g, void* l) {
    __builtin_amdgcn_global_load_lds(
        (const __attribute__((address_space(1))) void*)g,
        (__attribute__((address_space(3))) void*)l, 16, 0, 0);
}

__device__ __forceinline__ void vw8() { asm volatile("s_waitcnt vmcnt(8)"   ::: "memory"); __builtin_amdgcn_sched_barrier(0); }
__device__ __forceinline__ void vw0() { asm volatile("s_waitcnt vmcnt(0)"   ::: "memory"); __builtin_amdgcn_sched_barrier(0); }
__device__ __forceinline__ void lw8() { asm volatile("s_waitcnt lgkmcnt(8)" ::: "memory"); __builtin_amdgcn_sched_barrier(0); }
__device__ __forceinline__ void lw0() { asm volatile("s_waitcnt lgkmcnt(0)" ::: "memory"); __builtin_amdgcn_sched_barrier(0); }

// ---------------- Router: fp32 logits, top-2, softmax, counts, x->fp16 ----------------
__global__ __launch_bounds__(256) void k_router(
    const float* __restrict__ x, const float* __restrict__ Wr,
    unsigned short* __restrict__ xh, int* __restrict__ ctl,
    int* __restrict__ tok2e, float* __restrict__ tok2w)
{
    __shared__ float wr[NE * DIM];
    const int t = threadIdx.x;
#pragma unroll
    for (int i = 0; i < (NE * DIM) / 256; ++i) wr[i * 256 + t] = Wr[i * 256 + t];
    __syncthreads();

    const int lane = t & 63;
    const int n = blockIdx.x * 4 + (t >> 6);
    const float* xr = x + (size_t)n * DIM;
    unsigned short* xhr = xh + (size_t)n * DIM;

    float acc[NE];
#pragma unroll
    for (int e = 0; e < NE; ++e) acc[e] = 0.f;
#pragma unroll
    for (int j = 0; j < DIM / 64; ++j) {
        int d = j * 64 + lane;
        float v = xr[d];
        xhr[d] = f2h(v);
#pragma unroll
        for (int e = 0; e < NE; ++e) acc[e] += v * wr[e * DIM + d];
    }
#pragma unroll
    for (int off = 32; off >= 1; off >>= 1) {
#pragma unroll
        for (int e = 0; e < NE; ++e) acc[e] += __shfl_xor(acc[e], off);
    }
    if (lane == 0) {
        int e0 = 0; float v0 = acc[0];
#pragma unroll
        for (int e = 1; e < NE; ++e) if (acc[e] > v0) { v0 = acc[e]; e0 = e; }
        int e1 = -1; float v1 = -1e30f;
#pragma unroll
        for (int e = 0; e < NE; ++e) if (e != e0 && acc[e] > v1) { v1 = acc[e]; e1 = e; }
        float tt = expf(v1 - v0);
        tok2e[2 * n] = e0; tok2e[2 * n + 1] = e1;
        tok2w[2 * n] = 1.f / (1.f + tt); tok2w[2 * n + 1] = tt / (1.f + tt);
        atomicAdd(&ctl[e0], 1);
        atomicAdd(&ctl[e1], 1);
    }
}

// ---------------- Setup: 128-padded offsets, tile map, parallel pad fill ----------------
__global__ __launch_bounds__(256) void k_setup(
    int* __restrict__ ctl, int* __restrict__ tos, float* __restrict__ gos)
{
    __shared__ int off[NE], cnt[NE], ctile[NE + 1];
    const int t = threadIdx.x;
    if (t == 0) {
        int run = 0, T = 0;
        for (int e = 0; e < NE; ++e) {
            off[e] = run; cnt[e] = ctl[e]; ctile[e] = T;
            ctl[16 + e] = run;
            int mt = (cnt[e] + 127) >> 7;
            T += mt;
            run += mt << 7;
        }
        ctl[16 + NE] = run;
        ctl[33] = T; ctile[NE] = T;
    }
    __syncthreads();
    const int T = ctile[NE];
    if (t < T) {
        int e = 0;
#pragma unroll
        for (int k = 0; k < NE; ++k) if (t >= ctile[k + 1]) e = k + 1;
        ctl[184 + t] = e;
        ctl[320 + t] = off[e] + ((t - ctile[e]) << 7);
    }
    for (int e = 0; e < NE; ++e) {
        int c = cnt[e], pad = ((c + 127) >> 7) << 7;
        for (int s = c + t; s < pad; s += 256) { tos[off[e] + s] = 0; gos[off[e] + s] = 0.f; }
    }
}

// ---------------- Scatter ----------------
__global__ __launch_bounds__(256) void k_scatter(
    const int* __restrict__ tok2e, const float* __restrict__ tok2w,
    int* __restrict__ ctl, int* __restrict__ tos, float* __restrict__ gos)
{
    const int n = blockIdx.x * 256 + threadIdx.x;
#pragma unroll
    for (int k = 0; k < 2; ++k) {
        int e = tok2e[2 * n + k];
        int pos = atomicAdd(&ctl[8 + e], 1);
        int slot = ctl[16 + e] + pos;
        tos[slot] = n;
        gos[slot] = tok2w[2 * n + k];
    }
}

// ---------------- W convert: fp32 [E][KD][ND] -> fp16 tile-format ----------------
// element (k = kt*64 + c*8 + j, n) at Wt[((e*KT+kt)*ND + n)*64 + (c ^ (n&7))*8 + j]
__global__ __launch_bounds__(256) void k_wcvt(
    const float* __restrict__ W, unsigned short* __restrict__ Wt, int KD, int ND)
{
    __shared__ unsigned short Lt[64 * 66];   // pad 66: conflict-free transpose
    const int t = threadIdx.x;
    const int e = blockIdx.z, kt = blockIdx.y, n0 = blockIdx.x * 64;
    const int KT = KD >> 6;
    const float* src = W + (size_t)e * KD * ND + (size_t)(kt * 64) * ND + n0;
#pragma unroll
    for (int i = 0; i < 4; ++i) {
        int kl = (t >> 4) + i * 16;
        f32x4 r = *reinterpret_cast<const f32x4*>(src + (size_t)kl * ND + (t & 15) * 4);
        int j = kl & 7, co = kl >> 3;
#pragma unroll
        for (int m = 0; m < 4; ++m) {
            int nl = (t & 15) * 4 + m;
            Lt[nl * 66 + ((co ^ (nl & 7)) << 3) + j] = f2h(r[m]);
        }
    }
    __syncthreads();
    const int n = t >> 2, q = t & 3;
    unsigned short* dst = Wt + ((size_t)(e * KT + kt) * ND + n0 + n) * 64 + q * 16;
    const unsigned short* srcl = &Lt[n * 66 + q * 16];
    *reinterpret_cast<u32x4*>(dst)     = *reinterpret_cast<const u32x4*>(srcl);
    *reinterpret_cast<u32x4*>(dst + 8) = *reinterpret_cast<const u32x4*>(srcl + 8);
}

// ---- fragment load / mfma macros (static indices) ----
#define LDFRAG(Aout, Bout, BASE, H) do {                                     \
    const char* qa_ = (BASE) + (A0 ^ ((H) << 6));                            \
    const char* qb_ = (BASE) + (B0 ^ ((H) << 6));                            \
    _Pragma("unroll")                                                        \
    for (int i_ = 0; i_ < 4; ++i_) Aout[i_] = *(const f16x8*)(qa_ + i_ * 2048); \
    _Pragma("unroll")                                                        \
    for (int i_ = 0; i_ < 4; ++i_) Bout[i_] = *(const f16x8*)(qb_ + i_ * 2048); \
} while (0)

#define MMC(Af, Bf) do {                                                     \
    __builtin_amdgcn_s_setprio(1);                                           \
    _Pragma("unroll")                                                        \
    for (int mi_ = 0; mi_ < 4; ++mi_)                                        \
        _Pragma("unroll")                                                    \
        for (int ni_ = 0; ni_ < 4; ++ni_)                                    \
            acc[mi_][ni_] = __builtin_amdgcn_mfma_f32_16x16x32_f16(          \
                Af[mi_], Bf[ni_], acc[mi_][ni_], 0, 0, 0);                   \
    __builtin_amdgcn_s_setprio(0);                                           \
} while (0)

// ---------------- Pipelined grouped GEMM (128x128, BK=64, 4 waves, 2 blocks/CU) ----------------
// PHASE 1: gate*gelu(X@W1) -> H (tile-format). PHASE 2: H@W2 -> atomicAdd(out).
template <int PHASE>
__global__ __launch_bounds__(256) void k_gemmp(
    const unsigned short* __restrict__ Asrc, const unsigned short* __restrict__ Bh,
    unsigned short* __restrict__ Hout, float* __restrict__ Out,
    const int* __restrict__ ctl, const int* __restrict__ tos,
    const float* __restrict__ gos)
{
    constexpr int KD = (PHASE == 1) ? DIM : FF;
    constexpr int ND = (PHASE == 1) ? FF : DIM;
    constexpr int KT = KD / 64;
    constexpr int NX = ND / 128;

    // XCD-aware bijective remap: each XCD sweeps all N-tiles of one M-tile.
    const int lin = blockIdx.y * NX + blockIdx.x;
    const int xcd = lin & 7, chunk = lin >> 3;
    const int xp = chunk & (NX - 1);
    const int yp = (chunk / NX) * 8 + xcd;
    if (yp >= ctl[33]) return;
    const int e  = ctl[184 + yp];
    const int m0 = ctl[320 + yp];
    const int n0 = xp * 128;

    __shared__ __align__(1024) char lds[2 * 32768];

    const int t = threadIdx.x, l = t & 63, w = t >> 6;
    const int wm = w >> 1, wn = w & 1;

    // staging sources
    const char* ap[4]; const char* pa = nullptr; const char* pb;
    if constexpr (PHASE == 1) {
        const int swzb = ((l & 7) ^ ((l >> 3) & 7)) << 4;
#pragma unroll
        for (int i = 0; i < 4; ++i)
            ap[i] = (const char*)Asrc +
                    (size_t)tos[m0 + 32 * i + 8 * w + (l >> 3)] * (KD * 2) + swzb;
    } else {
        pa = (const char*)Asrc + (size_t)m0 * 128 + w * 1024 + l * 16;
    }
    pb = (const char*)Bh + ((size_t)e * KT * ND + n0) * 128 + w * 1024 + l * 16;

    auto STAGE = [&](int buf) {
        char* da = lds + buf * 32768 + w * 1024;
        char* db = lds + buf * 32768 + 16384 + w * 1024;
        if constexpr (PHASE == 1) {
#pragma unroll
            for (int i = 0; i < 4; ++i) { gl_lds16(ap[i], da + i * 4096); ap[i] += 128; }
        } else {
#pragma unroll
            for (int i = 0; i < 4; ++i) gl_lds16(pa + i * 4096, da + i * 4096);
            pa += (size_t)SLOT_CAP * 128;
        }
#pragma unroll
        for (int i = 0; i < 4; ++i) gl_lds16(pb + i * 4096, db + i * 4096);
        pb += (size_t)ND * 128;
    };

    // ds_read fragment bases (chunk-XOR swizzle baked; k-half1 = base ^ 64)
    const int fr = l & 15, hi = l >> 4;
    const int A0 = (wm * 64 + fr) * 128 + ((hi ^ (fr & 7)) << 4);
    const int B0 = 16384 + (wn * 64 + fr) * 128 + ((hi ^ (fr & 7)) << 4);

    f16x8 a0[4], b0[4], a1[4], b1[4];
    f32x4 acc[4][4];
#pragma unroll
    for (int a = 0; a < 4; ++a)
#pragma unroll
        for (int b = 0; b < 4; ++b) acc[a][b] = f32x4{0.f, 0.f, 0.f, 0.f};

    // prologue: stage tiles 0,1
    STAGE(0); STAGE(1);
    vw8();                                  // tile 0 landed (tile 1 in flight)
    __builtin_amdgcn_s_barrier();
    int cur = 0;

    for (int kt = 0; kt < KT - 2; ++kt) {
        const char* base = lds + cur * 32768;
        LDFRAG(a0, b0, base, 0);
        LDFRAG(a1, b1, base, 1);
        lw8();  MMC(a0, b0);
        lw0();                              // own reads of buf cur done
        __builtin_amdgcn_s_barrier();       // all waves done reading buf cur
        STAGE(cur);                         // tile kt+2 -> buf cur
        MMC(a1, b1);
        vw8();                              // tile kt+1 landed (kt+2 in flight)
        __builtin_amdgcn_s_barrier();
        cur ^= 1;
    }
    {   // tile KT-2 (no further staging)
        const char* base = lds + cur * 32768;
        LDFRAG(a0, b0, base, 0);
        LDFRAG(a1, b1, base, 1);
        lw8(); MMC(a0, b0);
        lw0(); MMC(a1, b1);
        vw0();                              // tile KT-1 fully landed
        __builtin_amdgcn_s_barrier();
        cur ^= 1;
    }
    {   // tile KT-1
        const char* base = lds + cur * 32768;
        LDFRAG(a0, b0, base, 0);
        LDFRAG(a1, b1, base, 1);
        lw8(); MMC(a0, b0);
        lw0(); MMC(a1, b1);
    }

    // epilogue
#pragma unroll
    for (int mi = 0; mi < 4; ++mi) {
#pragma unroll
        for (int rr = 0; rr < 4; ++rr) {
            const int srow = m0 + wm * 64 + mi * 16 + hi * 4 + rr;
            if constexpr (PHASE == 1) {
                const float gate = gos[srow];
#pragma unroll
                for (int ni = 0; ni < 4; ++ni) {
                    int col = n0 + wn * 64 + ni * 16 + fr;
                    float v = acc[mi][ni][rr];
                    float g = gate * 0.5f * v * (1.f + erff(v * 0.70710678118654752f));
                    int kl = col & 63;
                    Hout[((size_t)(col >> 6) * SLOT_CAP + srow) * 64 +
                         (((kl >> 3) ^ (srow & 7)) << 3) + (kl & 7)] = f2h(g);
                }
            } else {
                int tok = tos[srow];
                float* orow = Out + (size_t)tok * DIM + n0 + wn * 64 + fr;
#pragma unroll
                for (int ni = 0; ni < 4; ++ni)
                    atomicAdd(&orow[ni * 16], acc[mi][ni][rr]);
            }
        }
    }
}

// ---------------- Fallback 128-tile GEMM (reg-staged fp32 B; used if ws too small) ----------------
template <int PHASE>
__global__ __launch_bounds__(256) void k_gemm_fb(
    const unsigned short* __restrict__ Asrc, const float* __restrict__ Bf,
    unsigned short* __restrict__ Hout, float* __restrict__ Out,
    const int* __restrict__ ctl, const int* __restrict__ tos,
    const float* __restrict__ gos)
{
    constexpr int KD = (PHASE == 1) ? DIM : FF;
    constexpr int ND = (PHASE == 1) ? FF : DIM;
    constexpr int KT = KD / 64;

    const int tidx = blockIdx.y;
    if (tidx >= ctl[33]) return;
    const int e  = ctl[184 + tidx];
    const int m0 = ctl[320 + tidx];
    const int n0 = blockIdx.x * 128;

    __shared__ __align__(16) unsigned short Al[128 * 64];
    __shared__ __align__(16) unsigned short Bl[128 * 64];
    char* Alc = (char*)Al;
    char* Blc = (char*)Bl;

    const int t = threadIdx.x, lane = t & 63, wv = t >> 6;
    const int wm = wv >> 1, wn = wv & 1;

    const unsigned short* asrc[4];
    if (PHASE == 1) {
        const int swz = ((lane & 7) ^ (lane >> 3)) * 8;
#pragma unroll
        for (int i = 0; i < 4; ++i) {
            int row = i * 32 + wv * 8 + (lane >> 3);
            asrc[i] = Asrc + (size_t)tos[m0 + row] * KD + swz;
        }
    }
    const int lin = wv * 512 + lane * 8;

    f32x4 acc[4][4];
#pragma unroll
    for (int a = 0; a < 4; ++a)
#pragma unroll
        for (int b = 0; b < 4; ++b) acc[a][b] = f32x4{0.f, 0.f, 0.f, 0.f};

    for (int kt = 0; kt < KT; ++kt) {
        if (PHASE == 1) {
#pragma unroll
            for (int i = 0; i < 4; ++i)
                gl_lds16(asrc[i] + kt * 64, Al + i * 2048 + wv * 512);
        } else {
            const unsigned short* ab = Asrc + ((size_t)kt * SLOT_CAP + m0) * 64;
#pragma unroll
            for (int i = 0; i < 4; ++i)
                gl_lds16(ab + i * 2048 + lin, Al + i * 2048 + wv * 512);
        }
        {
            const float* Wf = Bf + (size_t)e * KD * ND;
            const int kb = (wv >> 1) * 32 + (lane >> 4) * 8;
            const int n4 = (wv & 1) * 64 + (lane & 15) * 4;
            f32x4 r[8];
#pragma unroll
            for (int rr = 0; rr < 8; ++rr)
                r[rr] = *reinterpret_cast<const f32x4*>(
                    Wf + (size_t)(kt * 64 + kb + rr) * ND + n0 + n4);
#pragma unroll
            for (int m = 0; m < 4; ++m) {
                f16x8 v;
#pragma unroll
                for (int rr = 0; rr < 8; ++rr) v[rr] = (_Float16)r[rr][m];
                int nn = n4 + m;
                *reinterpret_cast<f16x8*>(Blc + nn * 128 + (((kb >> 3) ^ (nn & 7)) << 4)) = v;
            }
        }
        __syncthreads();
#pragma unroll
        for (int kc = 0; kc < 2; ++kc) {
            const int cb = kc * 4 + (lane >> 4);
            f16x8 af[4], bf[4];
#pragma unroll
            for (int mi = 0; mi < 4; ++mi) {
                int row = wm * 64 + mi * 16 + (lane & 15);
                af[mi] = *reinterpret_cast<const f16x8*>(Alc + row * 128 + ((cb ^ (row & 7)) << 4));
            }
#pragma unroll
            for (int ni = 0; ni < 4; ++ni) {
                int col = wn * 64 + ni * 16 + (lane & 15);
                bf[ni] = *reinterpret_cast<const f16x8*>(Blc + col * 128 + ((cb ^ (col & 7)) << 4));
            }
#pragma unroll
            for (int mi = 0; mi < 4; ++mi)
#pragma unroll
                for (int ni = 0; ni < 4; ++ni)
                    acc[mi][ni] = __builtin_amdgcn_mfma_f32_16x16x32_f16(
                        af[mi], bf[ni], acc[mi][ni], 0, 0, 0);
        }
        __syncthreads();
    }

#pragma unroll
    for (int mi = 0; mi < 4; ++mi) {
#pragma unroll
        for (int rr = 0; rr < 4; ++rr) {
            const int srow = m0 + wm * 64 + mi * 16 + (lane >> 4) * 4 + rr;
            if (PHASE == 1) {
                const float gate = gos[srow];
#pragma unroll
                for (int ni = 0; ni < 4; ++ni) {
                    int col = n0 + wn * 64 + ni * 16 + (lane & 15);
                    float v = acc[mi][ni][rr];
                    float g = gate * 0.5f * v * (1.f + erff(v * 0.70710678118654752f));
                    int kl = col & 63;
                    Hout[((size_t)(col >> 6) * SLOT_CAP + srow) * 64 +
                         (((kl >> 3) ^ (srow & 7)) << 3) + (kl & 7)] = f2h(g);
                }
            } else {
                int tok = tos[srow];
                float* orow = Out + (size_t)tok * DIM + n0 + wn * 64 + (lane & 15);
#pragma unroll
                for (int ni = 0; ni < 4; ++ni)
                    atomicAdd(&orow[ni * 16], acc[mi][ni][rr]);
            }
        }
    }
}

// ---------------- launch ----------------
extern "C" void kernel_launch(void* const* d_in, const int* in_sizes, int n_in,
                              void* d_out, int out_size, void* d_ws, size_t ws_size,
                              hipStream_t stream) {
    (void)in_sizes; (void)n_in;
    const float* x  = (const float*)d_in[0];
    const float* Wr = (const float*)d_in[1];
    const float* W1 = (const float*)d_in[2];
    const float* W2 = (const float*)d_in[3];
    float* out = (float*)d_out;
    char* ws = (char*)d_ws;

    // ws layout (bytes):
    //   0          ctl (4 KB)
    //   4096       tok2e (64 KB)
    //   69632      tok2w (64 KB)
    //   135168     tos (17408*4)
    //   204800     gos (17408*4)
    //   274432     xh fp16 (16 MB)              -> 17,051,648
    //   17051648   H2 fp16 tile-fmt (142.6 MB)  -> 159,657,984
    //   159657984  Wt fp16 (64 MB, reused)      -> 226,766,848
    const size_t NEED_FB   = 159657984ULL;
    const size_t NEED_FULL = 226766848ULL;
    if (ws_size < NEED_FB) return;
    const bool big = ws_size >= NEED_FULL;

    int*            ctl = (int*)(ws + 0);
    int*            t2e = (int*)(ws + 4096);
    float*          t2w = (float*)(ws + 69632);
    int*            tos = (int*)(ws + 135168);
    float*          gos = (float*)(ws + 204800);
    unsigned short* xh  = (unsigned short*)(ws + 274432);
    unsigned short* H2  = (unsigned short*)(ws + 17051648);
    unsigned short* Wt  = (unsigned short*)(ws + 159657984);

    hipMemsetAsync(ctl, 0, 64, stream);
    hipMemsetAsync(d_out, 0, (size_t)out_size * 4, stream);

    k_router <<<dim3(N_TOK / 4), dim3(256), 0, stream>>>(x, Wr, xh, ctl, t2e, t2w);
    k_setup  <<<dim3(1), dim3(256), 0, stream>>>(ctl, tos, gos);
    k_scatter<<<dim3(N_TOK / 256), dim3(256), 0, stream>>>(t2e, t2w, ctl, tos, gos);

    if (big) {
        k_wcvt<<<dim3(64, 16, 8), dim3(256), 0, stream>>>(W1, Wt, DIM, FF);
        k_gemmp<1><<<dim3(FF / 128, MAXT), dim3(256), 0, stream>>>(
            xh, Wt, H2, nullptr, ctl, tos, gos);
        k_wcvt<<<dim3(16, 64, 8), dim3(256), 0, stream>>>(W2, Wt, FF, DIM);
        k_gemmp<2><<<dim3(DIM / 128, MAXT), dim3(256), 0, stream>>>(
            H2, Wt, nullptr, out, ctl, tos, gos);
    } else {
        k_gemm_fb<1><<<dim3(FF / 128, MAXT), dim3(256), 0, stream>>>(
            xh, W1, H2, nullptr, ctl, tos, gos);
        k_gemm_fb<2><<<dim3(DIM / 128, MAXT), dim3(256), 0, stream>>>(
            H2, W2, nullptr, out, ctl, tos, gos);
    }
}